// Round 4
// baseline (701.850 us; speedup 1.0000x reference)
//
#include <hip/hip_runtime.h>
#include <cstdint>
#include <cstddef>

// Problem constants
#define TT   2048
#define BB   64
#define KK   512
#define OO   512
#define NCH  64      // time chunks
#define TC   32      // t-steps per chunk (1 t-step per iteration)

typedef __attribute__((ext_vector_type(8))) short short8;
typedef __attribute__((ext_vector_type(4))) float f32x4;

__device__ __forceinline__ unsigned int f2bf(float f) {
  unsigned int u = __float_as_uint(f);
  unsigned int rounding = 0x7FFFu + ((u >> 16) & 1u);
  return (u + rounding) >> 16;
}

__device__ __forceinline__ float fast_sigmoid(float z) {
  // rcp(1+e^-z): v_exp+v_rcp, ~1ulp each — plenty under the bf16 threshold
  return __builtin_amdgcn_rcpf(1.0f + __expf(-z));
}

// ---------------- kernel 1: transpose+convert weights ----------------
// Gt[o][k] = bf16(g[k][o]); Ht likewise. grid (16,16,2), block (32,8)
__global__ void prep_weights_k(const float* __restrict__ g,
                               const float* __restrict__ h,
                               unsigned short* __restrict__ Gt,
                               unsigned short* __restrict__ Ht) {
  __shared__ float tile[32][33];
  const float* src = (blockIdx.z == 0) ? g : h;
  unsigned short* dst = (blockIdx.z == 0) ? Gt : Ht;
  int ox = blockIdx.x * 32;   // o base
  int ky = blockIdx.y * 32;   // k base
  int tx = threadIdx.x, ty = threadIdx.y;
  #pragma unroll
  for (int r = ty; r < 32; r += 8)
    tile[r][tx] = src[(ky + r) * OO + ox + tx];
  __syncthreads();
  #pragma unroll
  for (int r = ty; r < 32; r += 8)
    dst[(size_t)(ox + r) * KK + ky + tx] = (unsigned short)f2bf(tile[tx][r]);
}

// ---------------- kernel 2: fused convert + GEMM + gates + scan ----------
// 256 blocks (1/CU), 512 threads (8 waves = 2/SIMD). Weights in VGPRs:
// wave w owns o-cols [ot*128 + 16w, +16) of BOTH G and H (128 VGPRs).
// Per it = 1 t-step: x fp32 loaded coalesced to regs, packed to bf16,
// ds_write into XOR-swizzled LDS (dbuf, single barrier/it).
__global__ __launch_bounds__(512, 2) void rnn_fused4_k(
    const float* __restrict__ x,             // [T*B][K] fp32
    const unsigned short* __restrict__ Gt,   // [OO][KK] bf16
    const unsigned short* __restrict__ Ht,   // [OO][KK] bf16
    const float* __restrict__ gb, const float* __restrict__ hb,
    const float* __restrict__ r,  const float* __restrict__ rb,
    float* __restrict__ chunkA, float* __restrict__ chunkB) {
  extern __shared__ __align__(16) unsigned short smem[];  // 2 x [64][512] bf16

  const int tid  = threadIdx.x;
  const int wave = tid >> 6;   // 0..7
  const int lane = tid & 63;
  const int quad = lane >> 4;
  const int lcol = lane & 15;

  // bi = c*4 + ot: the 4 o-tile blocks of chunk c are dispatch-adjacent
  // (concurrent) so the chunk's x slice is shared in L2/LLC.
  const int bi = blockIdx.x;
  const int c  = bi >> 2;      // 0..63
  const int ot = bi & 3;       // 0..3
  const int o  = ot * 128 + wave * 16 + lcol;   // this thread's output column

  const float gbv = gb[o], hbv = hb[o];
  const float rv  = r[o],  rbv = rb[o];

  // ---- weights into registers: 16 cols x K512 x {G,H} = 128 VGPRs ----
  short8 Bg[8][2], Bh[8][2];
  {
    const unsigned short* gp = Gt + (size_t)o * KK + quad * 8;
    const unsigned short* hp = Ht + (size_t)o * KK + quad * 8;
    #pragma unroll
    for (int kc = 0; kc < 8; ++kc)
      #pragma unroll
      for (int ks = 0; ks < 2; ++ks) {
        Bg[kc][ks] = *(const short8*)(gp + kc * 64 + ks * 32);
        Bh[kc][ks] = *(const short8*)(hp + kc * 64 + ks * 32);
      }
  }

  // pack 8 float4s (one phase) to bf16 and ds_write_b64 into swizzled layout.
  // Lane's float4 #k holds els [k*256 + 4*lane, +4) of the wave's 8-row strip:
  // row = wave*8 + (k>>1), chunk = (k&1)*32 + (lane>>1), half = lane&1;
  // LDS slot s = (chunk&~7) | ((chunk&7) ^ (row&7)).
  auto cvt_write = [&](const float4* rg, int ph, int buf) {
    unsigned short* base = smem + buf * 32768;
    #pragma unroll
    for (int kk = 0; kk < 8; ++kk) {
      int k = ph * 8 + kk;
      int rlow = k >> 1;
      int row = wave * 8 + rlow;
      int chunk = (k & 1) * 32 + (lane >> 1);
      int slot = (chunk & ~7) | ((chunk & 7) ^ rlow);
      uint2 wv;
      wv.x = f2bf(rg[kk].x) | (f2bf(rg[kk].y) << 16);
      wv.y = f2bf(rg[kk].z) | (f2bf(rg[kk].w) << 16);
      *(uint2*)(base + row * 512 + slot * 8 + (lane & 1) * 4) = wv;
    }
  };
  // global base: wave's 8-row strip of t-step trow, as float4 (128/row)
  auto gsrc_of = [&](int trow) {
    return (const float4*)x + ((size_t)trow * BB + wave * 8) * (KK / 4) + lane;
  };

  // ---- initial stage of t = c*TC into buf 0 ----
  {
    const float4* gp = gsrc_of(c * TC);
    float4 rg[8];
    #pragma unroll
    for (int ph = 0; ph < 2; ++ph) {
      #pragma unroll
      for (int kk = 0; kk < 8; ++kk) rg[kk] = gp[(ph * 8 + kk) * 64];
      cvt_write(rg, ph, 0);
    }
  }

  // chunk-scan state per (b,o) slot: y_out = SB + SA*y_in
  float SA[16], SB[16];
  #pragma unroll
  for (int s = 0; s < 16; s++) { SA[s] = 1.0f; SB[s] = 0.0f; }

  f32x4 accG[4], accH[4];
  #pragma unroll
  for (int m = 0; m < 4; m++) {
    f32x4 z = {0.0f, 0.0f, 0.0f, 0.0f};
    accG[m] = z; accH[m] = z;
  }

  __syncthreads();

  int p = 0;
  for (int it = 0; it < TC; ++it) {
    const bool pf = (it + 1 < TC);
    const float4* gp = pf ? gsrc_of(c * TC + it + 1) : (const float4*)x;
    const unsigned short* A0 = smem + p * 32768;
    float4 rg[8];

    // phase-0 loads for t+1 (consumed after first MFMA half)
    if (pf) {
      #pragma unroll
      for (int kk = 0; kk < 8; ++kk) rg[kk] = gp[kk * 64];
    }

    // MFMA kc = 0..3
    #pragma unroll
    for (int kc = 0; kc < 4; ++kc)
      #pragma unroll
      for (int ks = 0; ks < 2; ++ks)
        #pragma unroll
        for (int mt = 0; mt < 4; ++mt) {
          int arow = mt * 16 + lcol;
          int slot = kc * 8 + ((ks * 4 + quad) ^ (arow & 7));
          short8 a = *(const short8*)(A0 + arow * 512 + slot * 8);
          accG[mt] = __builtin_amdgcn_mfma_f32_16x16x32_bf16(
              a, Bg[kc][ks], accG[mt], 0, 0, 0);
          accH[mt] = __builtin_amdgcn_mfma_f32_16x16x32_bf16(
              a, Bh[kc][ks], accH[mt], 0, 0, 0);
        }

    if (pf) {
      cvt_write(rg, 0, p ^ 1);
      #pragma unroll
      for (int kk = 0; kk < 8; ++kk) rg[kk] = gp[(8 + kk) * 64];
    }

    // MFMA kc = 4..7
    #pragma unroll
    for (int kc = 4; kc < 8; ++kc)
      #pragma unroll
      for (int ks = 0; ks < 2; ++ks)
        #pragma unroll
        for (int mt = 0; mt < 4; ++mt) {
          int arow = mt * 16 + lcol;
          int slot = kc * 8 + ((ks * 4 + quad) ^ (arow & 7));
          short8 a = *(const short8*)(A0 + arow * 512 + slot * 8);
          accG[mt] = __builtin_amdgcn_mfma_f32_16x16x32_bf16(
              a, Bg[kc][ks], accG[mt], 0, 0, 0);
          accH[mt] = __builtin_amdgcn_mfma_f32_16x16x32_bf16(
              a, Bh[kc][ks], accH[mt], 0, 0, 0);
        }

    // epilogue: one t-step of the recurrence, folded into (SA,SB)
    const int t = c * TC + it;
    const float rt = 2.0f * fast_sigmoid(((float)t * (1.0f / TT)) * rv + rbv);
    #pragma unroll
    for (int mt = 0; mt < 4; ++mt)
      #pragma unroll
      for (int reg = 0; reg < 4; ++reg) {
        float G = rt * fast_sigmoid(accG[mt][reg] + gbv);
        float eH = __expf(-2.0f * (accH[mt][reg] + hbv));
        float H = rt * fmaf(2.0f, __builtin_amdgcn_rcpf(1.0f + eH), -1.0f);
        int s = mt * 4 + reg;
        SB[s] = fmaf(G, SB[s], H);
        SA[s] *= G;
        accG[mt][reg] = 0.0f;
        accH[mt][reg] = 0.0f;
      }

    if (pf) cvt_write(rg, 1, p ^ 1);

    __syncthreads();   // ds_writes visible; releases buffer p
    p ^= 1;
  }

  // write chunk composition: layout [c][b][o]
  #pragma unroll
  for (int mt = 0; mt < 4; ++mt)
    #pragma unroll
    for (int reg = 0; reg < 4; ++reg) {
      int s = mt * 4 + reg;
      int b = mt * 16 + quad * 4 + reg;
      size_t idx = ((size_t)c * BB + b) * OO + o;
      chunkA[idx] = SA[s];
      chunkB[idx] = SB[s];
    }
}

// ---------------- kernel 3: fold chunks ----------------
__global__ void combine_k(const float* __restrict__ cA,
                          const float* __restrict__ cB,
                          float* __restrict__ out) {
  int i = blockIdx.x * blockDim.x + threadIdx.x;  // b*OO + o
  float y = 0.0f;
  #pragma unroll 8
  for (int c = 0; c < NCH; c++) {
    float A  = cA[(size_t)c * (BB * OO) + i];
    float Bv = cB[(size_t)c * (BB * OO) + i];
    y = fmaf(A, y, Bv);
  }
  out[i] = y;
}

extern "C" void kernel_launch(void* const* d_in, const int* in_sizes, int n_in,
                              void* d_out, int out_size, void* d_ws, size_t ws_size,
                              hipStream_t stream) {
  (void)in_sizes; (void)n_in; (void)out_size; (void)ws_size;
  const float* x  = (const float*)d_in[0];
  const float* g  = (const float*)d_in[1];
  const float* gb = (const float*)d_in[2];
  const float* h  = (const float*)d_in[3];
  const float* hb = (const float*)d_in[4];
  const float* r  = (const float*)d_in[5];
  const float* rb = (const float*)d_in[6];
  float* out = (float*)d_out;

  char* w = (char*)d_ws;
  unsigned short* Gt = (unsigned short*)w;                  // 524288 B
  unsigned short* Ht = (unsigned short*)(w + 524288);       // 524288 B
  float* chunkA = (float*)(w + 1048576);                    // 8388608 B
  float* chunkB = (float*)(w + 9437184);                    // 8388608 B
  // total: 17825792 B

  static bool attr_set = false;
  if (!attr_set) {
    hipFuncSetAttribute(reinterpret_cast<const void*>(rnn_fused4_k),
                        hipFuncAttributeMaxDynamicSharedMemorySize, 131072);
    attr_set = true;
  }

  prep_weights_k<<<dim3(16, 16, 2), dim3(32, 8), 0, stream>>>(g, h, Gt, Ht);
  rnn_fused4_k<<<NCH * 4, 512, 131072, stream>>>(x, Gt, Ht, gb, hb, r, rb,
                                                 chunkA, chunkB);
  combine_k<<<(BB * OO) / 256, 256, 0, stream>>>(chunkA, chunkB, out);
}